// Round 3
// baseline (1808.438 us; speedup 1.0000x reference)
//
#include <hip/hip_runtime.h>

#define BATCH 8192
#define NSTEP 29
#define BTILE 32
#define BT    1024         // 16 waves
#define XS    72           // x stride (bf16): [0,48)=tactile/out4, [48,54)=act, [54,60)=state, [60]=1
#define HS    232          // h1 stride: [0,200)=h, [208]=1
#define H2S   296          // h2cat stride: [0,200)=h2, [208,256)=inp, [256]=1
#define OS    232          // o3 stride: [0,200)=o3, [208]=1

// fragment-packed weights: each (tile,kc,gate) = 512 contiguous elems (lane*8+e)
#define OW1   0            // W1: [13][9][4][512]
#define OW2   239616       // W2: [13][14][4][512]
#define OF1   612352       // FC1: [13][9][512]
#define OF2   672256       // FC2: [3][7][512]
#define WTOT  683008

typedef __bf16 bf16x8 __attribute__((ext_vector_type(8)));
typedef float  f32x4  __attribute__((ext_vector_type(4)));

__device__ __forceinline__ unsigned short f2bf(float f) {
    union { float f; unsigned u; } v; v.f = f;
    unsigned r = v.u + 0x7fffu + ((v.u >> 16) & 1u);
    return (unsigned short)(r >> 16);
}
__device__ __forceinline__ float sigf(float x) { return 1.0f / (1.0f + __expf(-x)); }
__device__ __forceinline__ float tanh_(float x) {
    x = fminf(15.0f, fmaxf(-15.0f, x));
    float e = __expf(2.0f * x);
    return (e - 1.0f) / (e + 1.0f);
}

// repack weights into per-wave fragment order (coalesced 1KB bursts), bias folded as K-col
__global__ void actp_prep(const float* __restrict__ wih1, const float* __restrict__ whh1,
                          const float* __restrict__ bih1, const float* __restrict__ bhh1,
                          const float* __restrict__ wih2, const float* __restrict__ whh2,
                          const float* __restrict__ bih2, const float* __restrict__ bhh2,
                          const float* __restrict__ fc1w, const float* __restrict__ fc1b,
                          const float* __restrict__ fc2w, const float* __restrict__ fc2b,
                          unsigned short* __restrict__ ws) {
    int i = blockIdx.x * 256 + threadIdx.x;
    if (i >= WTOT) return;
    float v = 0.f;
    if (i < OW2) {                               // W1 [13][9][4][512], K: x(64)|h1(224)
        int blk = i >> 9, le = i & 511;
        int lane = le >> 3, e = le & 7;
        int g = blk & 3, t2 = blk >> 2;
        int kc = t2 % 9, jt = t2 / 9;
        int n = jt * 16 + (lane & 15), k = kc * 32 + (lane >> 4) * 8 + e;
        if (n < 200) {
            int o = g * 200 + n;
            if (k < 60)                   v = wih1[o * 60 + k];
            else if (k == 60)             v = bih1[o] + bhh1[o];
            else if (k >= 64 && k < 264)  v = whh1[o * 200 + (k - 64)];
        }
    } else if (i < OF1) {                        // W2 [13][14][4][512], K: h1(224)|h2(224)
        int j = i - OW2;
        int blk = j >> 9, le = j & 511;
        int lane = le >> 3, e = le & 7;
        int g = blk & 3, t2 = blk >> 2;
        int kc = t2 % 14, jt = t2 / 14;
        int n = jt * 16 + (lane & 15), k = kc * 32 + (lane >> 4) * 8 + e;
        if (n < 200) {
            int o = g * 200 + n;
            if (k < 200)                   v = wih2[o * 200 + k];
            else if (k == 208)             v = bih2[o] + bhh2[o];
            else if (k >= 224 && k < 424)  v = whh2[o * 200 + (k - 224)];
        }
    } else if (i < OF2) {                        // FC1 [13][9][512], K: h2(200..)|inp(208..256)|bias(256)
        int j = i - OF1;
        int blk = j >> 9, le = j & 511;
        int lane = le >> 3, e = le & 7;
        int kc = blk % 9, jt = blk / 9;
        int n = jt * 16 + (lane & 15), k = kc * 32 + (lane >> 4) * 8 + e;
        if (n < 200) {
            if (k < 200)                   v = fc1w[n * 248 + k];
            else if (k >= 208 && k < 256)  v = fc1w[n * 248 + 200 + (k - 208)];
            else if (k == 256)             v = fc1b[n];
        }
    } else {                                     // FC2 [3][7][512], K: o3(200)|bias(208)
        int j = i - OF2;
        int blk = j >> 9, le = j & 511;
        int lane = le >> 3, e = le & 7;
        int kc = blk % 7, nt = blk / 7;
        int n = nt * 16 + (lane & 15), k = kc * 32 + (lane >> 4) * 8 + e;
        if (k < 200)       v = fc2w[n * 200 + k];
        else if (k == 208) v = fc2b[n];
    }
    ws[i] = (v == 0.f) ? (unsigned short)0 : f2bf(v);
}

// 4-gate MFMA tile + in-register LSTM elementwise; bp already includes lane*8.
template<int NKC, int SPLIT, int SA0, int SA1, int KOFF1>
__device__ __forceinline__ void lstm_tile(
    const unsigned short* a0buf, const unsigned short* a1buf,
    const unsigned short* bp,
    const int lrow, const int lgrp,
    float (&cst)[2][4],
    unsigned short* hout, const int hstride, const int jcol)
{
    f32x4 acc[4][2];
#pragma unroll
    for (int g = 0; g < 4; ++g) { acc[g][0] = {0.f,0.f,0.f,0.f}; acc[g][1] = {0.f,0.f,0.f,0.f}; }
#pragma unroll
    for (int kc = 0; kc < NKC; ++kc) {
        const int koff = kc * 32 + lgrp * 8;
        bf16x8 a0, a1;
        if (kc < SPLIT) {
            a0 = *(const bf16x8*)(a0buf + lrow * SA0 + koff);
            a1 = *(const bf16x8*)(a0buf + (lrow + 16) * SA0 + koff);
        } else {
            a0 = *(const bf16x8*)(a1buf + lrow * SA1 + koff - KOFF1);
            a1 = *(const bf16x8*)(a1buf + (lrow + 16) * SA1 + koff - KOFF1);
        }
#pragma unroll
        for (int g = 0; g < 4; ++g) {
            bf16x8 b = *(const bf16x8*)(bp + (kc * 4 + g) * 512);
            acc[g][0] = __builtin_amdgcn_mfma_f32_16x16x32_bf16(a0, b, acc[g][0], 0, 0, 0);
            acc[g][1] = __builtin_amdgcn_mfma_f32_16x16x32_bf16(a1, b, acc[g][1], 0, 0, 0);
        }
    }
#pragma unroll
    for (int m = 0; m < 2; ++m)
#pragma unroll
    for (int r = 0; r < 4; ++r) {
        float c = sigf(acc[1][m][r]) * cst[m][r] + sigf(acc[0][m][r]) * tanh_(acc[2][m][r]);
        cst[m][r] = c;
        hout[(m * 16 + lgrp * 4 + r) * hstride + jcol] = f2bf(sigf(acc[3][m][r]) * tanh_(c));
    }
}

__global__ __launch_bounds__(BT, 4) void actp_main(
    const float* __restrict__ tact, const float* __restrict__ acts,
    const unsigned short* __restrict__ ws, float* __restrict__ out)
{
    __shared__ alignas(16) unsigned short xbuf[BTILE * XS];
    __shared__ alignas(16) unsigned short h1buf[2][BTILE * HS];
    __shared__ alignas(16) unsigned short h2cat[2][BTILE * H2S];
    __shared__ alignas(16) unsigned short o3buf[BTILE * OS];

    const int tid  = threadIdx.x;
    const int lane = tid & 63;
    const int wid  = tid >> 6;      // 0..15
    const int lrow = lane & 15;
    const int lgrp = lane >> 4;
    const int r0   = blockIdx.x * BTILE;

    // per-wave fragment-packed weight bases (include lane*8)
    const unsigned short* tb1 = ws + OW1 + wid * (9 * 4 * 512)  + (lane << 3);
    const unsigned short* tb2 = ws + OW2 + wid * (14 * 4 * 512) + (lane << 3);
    const unsigned short* tf1 = ws + OF1 + wid * (9 * 512)      + (lane << 3);
    const unsigned short* tf2 = ws + OF2 + wid * (7 * 512)      + (lane << 3);

    // ---- prologue ----
    for (int i = tid; i < BTILE * XS;      i += BT) xbuf[i] = 0;
    for (int i = tid; i < 2 * BTILE * HS;  i += BT) h1buf[0][i] = 0;
    for (int i = tid; i < 2 * BTILE * H2S; i += BT) h2cat[0][i] = 0;
    for (int i = tid; i < BTILE * OS;      i += BT) o3buf[i] = 0;
    __syncthreads();
    if (tid < BTILE) {
        const unsigned short ONE = 0x3F80;
        xbuf[tid * XS + 60] = ONE;
        h1buf[0][tid * HS + 208] = ONE;  h1buf[1][tid * HS + 208] = ONE;
        h2cat[0][tid * H2S + 256] = ONE; h2cat[1][tid * H2S + 256] = ONE;
        o3buf[tid * OS + 208] = ONE;
    }
    if (tid < BTILE * 6) {
        int b = tid / 6, m = tid - b * 6;
        xbuf[b * XS + 54 + m] = f2bf(acts[(size_t)(r0 + b) * 6 + m]);                 // state = acts[0]
        xbuf[b * XS + 48 + m] = f2bf(acts[((size_t)1 * BATCH + r0 + b) * 6 + m]);     // action step 0
    }
    for (int i = tid; i < BTILE * 48; i += BT) {
        int b = i / 48, j = i - b * 48;
        unsigned short v = f2bf(tact[(size_t)(r0 + b) * 48 + j]);                      // tact[0]
        xbuf[b * XS + j] = v;
        h2cat[0][b * H2S + 208 + j] = v;
    }
    __syncthreads();

    float c1[2][4], c2[2][4];
#pragma unroll
    for (int m = 0; m < 2; ++m)
#pragma unroll
    for (int r = 0; r < 4; ++r) { c1[m][r] = 0.f; c2[m][r] = 0.f; }

    for (int idx = 0; idx < NSTEP; ++idx) {
        const int p = idx & 1;
        unsigned short* h1n = h1buf[p];
        unsigned short* h1o = h1buf[p ^ 1];
        unsigned short* h2n = h2cat[p];
        unsigned short* h2o = h2cat[p ^ 1];

        // ---- P1: LSTM1 (x | h1_old) -> h1_new ----
        if (wid < 13) {
            const int n = wid * 16 + lrow;
            lstm_tile<9, 2, XS, HS, 64>(xbuf, h1o, tb1, lrow, lgrp, c1, h1n, HS, n);
        }
        __syncthreads();

        // ---- P2: LSTM2 (h1_new | h2_old) -> h2_new ----
        if (wid < 13) {
            const int n = wid * 16 + lrow;
            lstm_tile<14, 7, HS, H2S, 224>(h1n, h2o, tb2, lrow, lgrp, c2, h2n, H2S, n);
        }
        __syncthreads();

        // ---- P3: FC1 (h2_new|inp|1) -> o3 ; next-step input preloads ----
        if (wid < 13) {
            const int n = wid * 16 + lrow;
            f32x4 a0c = {0.f,0.f,0.f,0.f}, a1c = {0.f,0.f,0.f,0.f};
#pragma unroll
            for (int kc = 0; kc < 9; ++kc) {
                const int koff = kc * 32 + lgrp * 8;
                bf16x8 a0 = *(const bf16x8*)(h2n + lrow * H2S + koff);
                bf16x8 a1 = *(const bf16x8*)(h2n + (lrow + 16) * H2S + koff);
                bf16x8 b  = *(const bf16x8*)(tf1 + kc * 512);
                a0c = __builtin_amdgcn_mfma_f32_16x16x32_bf16(a0, b, a0c, 0, 0, 0);
                a1c = __builtin_amdgcn_mfma_f32_16x16x32_bf16(a1, b, a1c, 0, 0, 0);
            }
#pragma unroll
            for (int r = 0; r < 4; ++r) {
                o3buf[(lgrp * 4 + r) * OS + n]      = f2bf(tanh_(a0c[r]));
                o3buf[(16 + lgrp * 4 + r) * OS + n] = f2bf(tanh_(a1c[r]));
            }
        }
        if (idx < NSTEP - 1) {
            if (tid < BTILE * 6) {           // action for step idx+1 = acts[idx+2]
                int b = tid / 6, m = tid - b * 6;
                xbuf[b * XS + 48 + m] = f2bf(acts[((size_t)(idx + 2) * BATCH + r0 + b) * 6 + m]);
            }
            if (idx < 9) {                   // ground-truth tactile for step idx+1
                for (int i = tid; i < BTILE * 48; i += BT) {
                    int b = i / 48, j = i - b * 48;
                    unsigned short v = f2bf(tact[((size_t)(idx + 1) * BATCH + r0 + b) * 48 + j]);
                    xbuf[b * XS + j] = v;
                    h2cat[p ^ 1][b * H2S + 208 + j] = v;
                }
            }
        }
        __syncthreads();

        // ---- P4: FC2 (o3|1) -> out4 ; emit + feedback ----
        if (wid < 3) {
            const int n = wid * 16 + lrow;   // 0..47
            f32x4 a0c = {0.f,0.f,0.f,0.f}, a1c = {0.f,0.f,0.f,0.f};
#pragma unroll
            for (int kc = 0; kc < 7; ++kc) {
                const int koff = kc * 32 + lgrp * 8;
                bf16x8 a0 = *(const bf16x8*)(o3buf + lrow * OS + koff);
                bf16x8 a1 = *(const bf16x8*)(o3buf + (lrow + 16) * OS + koff);
                bf16x8 b  = *(const bf16x8*)(tf2 + kc * 512);
                a0c = __builtin_amdgcn_mfma_f32_16x16x32_bf16(a0, b, a0c, 0, 0, 0);
                a1c = __builtin_amdgcn_mfma_f32_16x16x32_bf16(a1, b, a1c, 0, 0, 0);
            }
            if (idx >= 9) {
#pragma unroll
                for (int m = 0; m < 2; ++m)
#pragma unroll
                for (int r = 0; r < 4; ++r) {
                    const int row = m * 16 + lgrp * 4 + r;
                    float o4 = tanh_(m == 0 ? a0c[r] : a1c[r]);
                    out[((size_t)(idx - 9) * BATCH + r0 + row) * 48 + n] = o4;
                    unsigned short v = f2bf(o4);
                    xbuf[row * XS + n] = v;
                    h2cat[p ^ 1][row * H2S + 208 + n] = v;
                }
            }
        }
        __syncthreads();
    }
}

extern "C" void kernel_launch(void* const* d_in, const int* in_sizes, int n_in,
                              void* d_out, int out_size, void* d_ws, size_t ws_size,
                              hipStream_t stream) {
    (void)in_sizes; (void)n_in; (void)out_size; (void)ws_size;
    const float* tact = (const float*)d_in[0];
    const float* acts = (const float*)d_in[1];
    const float* wih1 = (const float*)d_in[2];
    const float* whh1 = (const float*)d_in[3];
    const float* bih1 = (const float*)d_in[4];
    const float* bhh1 = (const float*)d_in[5];
    const float* wih2 = (const float*)d_in[6];
    const float* whh2 = (const float*)d_in[7];
    const float* bih2 = (const float*)d_in[8];
    const float* bhh2 = (const float*)d_in[9];
    const float* fc1w = (const float*)d_in[10];
    const float* fc1b = (const float*)d_in[11];
    const float* fc2w = (const float*)d_in[12];
    const float* fc2b = (const float*)d_in[13];
    unsigned short* ws = (unsigned short*)d_ws;
    float* outp = (float*)d_out;

    actp_prep<<<(WTOT + 255) / 256, 256, 0, stream>>>(wih1, whh1, bih1, bhh1,
                                                      wih2, whh2, bih2, bhh2,
                                                      fc1w, fc1b, fc2w, fc2b, ws);
    actp_main<<<BATCH / BTILE, BT, 0, stream>>>(tact, acts, ws, outp);
}

// Round 4
// 1780.558 us; speedup vs baseline: 1.0157x; 1.0157x over previous
//
#include <hip/hip_runtime.h>

#define BATCH 8192
#define NSTEP 29
#define BTILE 32
#define BT    1024         // 16 waves
#define XS    72           // x stride (bf16): [0,48)=tactile/out4, [48,54)=act, [54,60)=state, [60]=1
#define HS    232          // h1 stride: [0,200)=h, [208]=1
#define H2S   296          // h2cat stride: [0,200)=h2, [208,256)=inp, [256]=1
#define OS    232          // o3 stride: [0,200)=o3, [208]=1

// fragment-packed weights: each (tile,kc,gate) = 512 contiguous elems (lane*8+e)
#define OW1   0            // W1: [13][9][4][512]
#define OW2   239616       // W2: [13][14][4][512]
#define OF1   612352       // FC1: [13][9][512]
#define OF2   672256       // FC2: [3][7][512]
#define WTOT  683008

typedef __bf16 bf16x8 __attribute__((ext_vector_type(8)));
typedef float  f32x4  __attribute__((ext_vector_type(4)));

__device__ __forceinline__ unsigned short f2bf(float f) {
    union { float f; unsigned u; } v; v.f = f;
    unsigned r = v.u + 0x7fffu + ((v.u >> 16) & 1u);
    return (unsigned short)(r >> 16);
}
__device__ __forceinline__ float sigf(float x) { return 1.0f / (1.0f + __expf(-x)); }
__device__ __forceinline__ float tanh_(float x) {
    x = fminf(15.0f, fmaxf(-15.0f, x));
    float e = __expf(2.0f * x);
    return (e - 1.0f) / (e + 1.0f);
}

// repack weights into per-wave fragment order (coalesced 1KB bursts), bias folded as K-col
__global__ void actp_prep(const float* __restrict__ wih1, const float* __restrict__ whh1,
                          const float* __restrict__ bih1, const float* __restrict__ bhh1,
                          const float* __restrict__ wih2, const float* __restrict__ whh2,
                          const float* __restrict__ bih2, const float* __restrict__ bhh2,
                          const float* __restrict__ fc1w, const float* __restrict__ fc1b,
                          const float* __restrict__ fc2w, const float* __restrict__ fc2b,
                          unsigned short* __restrict__ ws) {
    int i = blockIdx.x * 256 + threadIdx.x;
    if (i >= WTOT) return;
    float v = 0.f;
    if (i < OW2) {                               // W1 [13][9][4][512], K: x(64)|h1(224)
        int blk = i >> 9, le = i & 511;
        int lane = le >> 3, e = le & 7;
        int g = blk & 3, t2 = blk >> 2;
        int kc = t2 % 9, jt = t2 / 9;
        int n = jt * 16 + (lane & 15), k = kc * 32 + (lane >> 4) * 8 + e;
        if (n < 200) {
            int o = g * 200 + n;
            if (k < 60)                   v = wih1[o * 60 + k];
            else if (k == 60)             v = bih1[o] + bhh1[o];
            else if (k >= 64 && k < 264)  v = whh1[o * 200 + (k - 64)];
        }
    } else if (i < OF1) {                        // W2 [13][14][4][512], K: h1(224)|h2(224)
        int j = i - OW2;
        int blk = j >> 9, le = j & 511;
        int lane = le >> 3, e = le & 7;
        int g = blk & 3, t2 = blk >> 2;
        int kc = t2 % 14, jt = t2 / 14;
        int n = jt * 16 + (lane & 15), k = kc * 32 + (lane >> 4) * 8 + e;
        if (n < 200) {
            int o = g * 200 + n;
            if (k < 200)                   v = wih2[o * 200 + k];
            else if (k == 208)             v = bih2[o] + bhh2[o];
            else if (k >= 224 && k < 424)  v = whh2[o * 200 + (k - 224)];
        }
    } else if (i < OF2) {                        // FC1 [13][9][512]
        int j = i - OF1;
        int blk = j >> 9, le = j & 511;
        int lane = le >> 3, e = le & 7;
        int kc = blk % 9, jt = blk / 9;
        int n = jt * 16 + (lane & 15), k = kc * 32 + (lane >> 4) * 8 + e;
        if (n < 200) {
            if (k < 200)                   v = fc1w[n * 248 + k];
            else if (k >= 208 && k < 256)  v = fc1w[n * 248 + 200 + (k - 208)];
            else if (k == 256)             v = fc1b[n];
        }
    } else {                                     // FC2 [3][7][512]
        int j = i - OF2;
        int blk = j >> 9, le = j & 511;
        int lane = le >> 3, e = le & 7;
        int kc = blk % 7, nt = blk / 7;
        int n = nt * 16 + (lane & 15), k = kc * 32 + (lane >> 4) * 8 + e;
        if (k < 200)       v = fc2w[n * 200 + k];
        else if (k == 208) v = fc2b[n];
    }
    ws[i] = (v == 0.f) ? (unsigned short)0 : f2bf(v);
}

// 4-gate MFMA tile + in-register LSTM elementwise.
// Triple-buffered register prefetch of B fragments: slot reuse (WAR) caps live
// range at 12 frags while keeping ~8 loads in flight per wave.
template<int NKC, int SPLIT, int SA0, int SA1, int KOFF1>
__device__ __forceinline__ void lstm_tile(
    const unsigned short* a0buf, const unsigned short* a1buf,
    const unsigned short* bp,
    const int lrow, const int lgrp,
    float (&cst)[2][4],
    unsigned short* hout, const int hstride, const int jcol)
{
    f32x4 acc[4][2];
#pragma unroll
    for (int g = 0; g < 4; ++g) { acc[g][0] = {0.f,0.f,0.f,0.f}; acc[g][1] = {0.f,0.f,0.f,0.f}; }

    bf16x8 wb[3][4];
#pragma unroll
    for (int s = 0; s < 2; ++s)
#pragma unroll
    for (int g = 0; g < 4; ++g)
        wb[s][g] = *(const bf16x8*)(bp + (s * 4 + g) * 512);

#pragma unroll
    for (int kc = 0; kc < NKC; ++kc) {
        const int slot  = kc % 3;
        const int nslot = (kc + 2) % 3;
        if (kc + 2 < NKC) {
#pragma unroll
            for (int g = 0; g < 4; ++g)
                wb[nslot][g] = *(const bf16x8*)(bp + ((kc + 2) * 4 + g) * 512);
        }
        const int koff = kc * 32 + lgrp * 8;
        bf16x8 a0, a1;
        if (kc < SPLIT) {
            a0 = *(const bf16x8*)(a0buf + lrow * SA0 + koff);
            a1 = *(const bf16x8*)(a0buf + (lrow + 16) * SA0 + koff);
        } else {
            a0 = *(const bf16x8*)(a1buf + lrow * SA1 + koff - KOFF1);
            a1 = *(const bf16x8*)(a1buf + (lrow + 16) * SA1 + koff - KOFF1);
        }
#pragma unroll
        for (int g = 0; g < 4; ++g) {
            acc[g][0] = __builtin_amdgcn_mfma_f32_16x16x32_bf16(a0, wb[slot][g], acc[g][0], 0, 0, 0);
            acc[g][1] = __builtin_amdgcn_mfma_f32_16x16x32_bf16(a1, wb[slot][g], acc[g][1], 0, 0, 0);
        }
    }
#pragma unroll
    for (int m = 0; m < 2; ++m)
#pragma unroll
    for (int r = 0; r < 4; ++r) {
        float c = sigf(acc[1][m][r]) * cst[m][r] + sigf(acc[0][m][r]) * tanh_(acc[2][m][r]);
        cst[m][r] = c;
        hout[(m * 16 + lgrp * 4 + r) * hstride + jcol] = f2bf(sigf(acc[3][m][r]) * tanh_(c));
    }
}

__global__ __launch_bounds__(BT, 4) void actp_main(
    const float* __restrict__ tact, const float* __restrict__ acts,
    const unsigned short* __restrict__ ws, float* __restrict__ out)
{
    __shared__ alignas(16) unsigned short xbuf[BTILE * XS];
    __shared__ alignas(16) unsigned short h1buf[2][BTILE * HS];
    __shared__ alignas(16) unsigned short h2cat[2][BTILE * H2S];
    __shared__ alignas(16) unsigned short o3buf[BTILE * OS];

    const int tid  = threadIdx.x;
    const int lane = tid & 63;
    const int wid  = tid >> 6;      // 0..15
    const int lrow = lane & 15;
    const int lgrp = lane >> 4;
    const int r0   = blockIdx.x * BTILE;

    // per-wave fragment-packed weight bases (include lane*8)
    const unsigned short* tb1 = ws + OW1 + wid * (9 * 4 * 512)  + (lane << 3);
    const unsigned short* tb2 = ws + OW2 + wid * (14 * 4 * 512) + (lane << 3);
    const unsigned short* tf1 = ws + OF1 + wid * (9 * 512)      + (lane << 3);
    const unsigned short* tf2 = ws + OF2 + (wid < 3 ? wid : 0) * (7 * 512) + (lane << 3);

    // ---- prologue ----
    for (int i = tid; i < BTILE * XS;      i += BT) xbuf[i] = 0;
    for (int i = tid; i < 2 * BTILE * HS;  i += BT) h1buf[0][i] = 0;
    for (int i = tid; i < 2 * BTILE * H2S; i += BT) h2cat[0][i] = 0;
    for (int i = tid; i < BTILE * OS;      i += BT) o3buf[i] = 0;
    __syncthreads();
    if (tid < BTILE) {
        const unsigned short ONE = 0x3F80;
        xbuf[tid * XS + 60] = ONE;
        h1buf[0][tid * HS + 208] = ONE;  h1buf[1][tid * HS + 208] = ONE;
        h2cat[0][tid * H2S + 256] = ONE; h2cat[1][tid * H2S + 256] = ONE;
        o3buf[tid * OS + 208] = ONE;
    }
    if (tid < BTILE * 6) {
        int b = tid / 6, m = tid - b * 6;
        xbuf[b * XS + 54 + m] = f2bf(acts[(size_t)(r0 + b) * 6 + m]);                 // state = acts[0]
        xbuf[b * XS + 48 + m] = f2bf(acts[((size_t)1 * BATCH + r0 + b) * 6 + m]);     // action step 0
    }
    for (int i = tid; i < BTILE * 48; i += BT) {
        int b = i / 48, j = i - b * 48;
        unsigned short v = f2bf(tact[(size_t)(r0 + b) * 48 + j]);                      // tact[0]
        xbuf[b * XS + j] = v;
        h2cat[0][b * H2S + 208 + j] = v;
    }
    __syncthreads();

    float c1[2][4], c2[2][4];
#pragma unroll
    for (int m = 0; m < 2; ++m)
#pragma unroll
    for (int r = 0; r < 4; ++r) { c1[m][r] = 0.f; c2[m][r] = 0.f; }

    for (int idx = 0; idx < NSTEP; ++idx) {
        const int p = idx & 1;
        unsigned short* h1n = h1buf[p];
        unsigned short* h1o = h1buf[p ^ 1];
        unsigned short* h2n = h2cat[p];
        unsigned short* h2o = h2cat[p ^ 1];

        // ---- P1: LSTM1 (x | h1_old) -> h1_new ----
        if (wid < 13) {
            const int n = wid * 16 + lrow;
            lstm_tile<9, 2, XS, HS, 64>(xbuf, h1o, tb1, lrow, lgrp, c1, h1n, HS, n);
        }
        __syncthreads();

        // ---- P2: LSTM2 (h1_new | h2_old) -> h2_new ----
        if (wid < 13) {
            const int n = wid * 16 + lrow;
            lstm_tile<14, 7, HS, H2S, 224>(h1n, h2o, tb2, lrow, lgrp, c2, h2n, H2S, n);
        }
        __syncthreads();

        // ---- P3: FC1 (h2_new|inp|1) -> o3 ; next-step input preloads ----
        if (wid < 13) {
            const int n = wid * 16 + lrow;
            bf16x8 wf[9];
#pragma unroll
            for (int kc = 0; kc < 9; ++kc) wf[kc] = *(const bf16x8*)(tf1 + kc * 512);
            f32x4 a0c = {0.f,0.f,0.f,0.f}, a1c = {0.f,0.f,0.f,0.f};
#pragma unroll
            for (int kc = 0; kc < 9; ++kc) {
                const int koff = kc * 32 + lgrp * 8;
                bf16x8 a0 = *(const bf16x8*)(h2n + lrow * H2S + koff);
                bf16x8 a1 = *(const bf16x8*)(h2n + (lrow + 16) * H2S + koff);
                a0c = __builtin_amdgcn_mfma_f32_16x16x32_bf16(a0, wf[kc], a0c, 0, 0, 0);
                a1c = __builtin_amdgcn_mfma_f32_16x16x32_bf16(a1, wf[kc], a1c, 0, 0, 0);
            }
#pragma unroll
            for (int r = 0; r < 4; ++r) {
                o3buf[(lgrp * 4 + r) * OS + n]      = f2bf(tanh_(a0c[r]));
                o3buf[(16 + lgrp * 4 + r) * OS + n] = f2bf(tanh_(a1c[r]));
            }
        }
        if (idx < NSTEP - 1) {
            if (tid < BTILE * 6) {           // action for step idx+1 = acts[idx+2]
                int b = tid / 6, m = tid - b * 6;
                xbuf[b * XS + 48 + m] = f2bf(acts[((size_t)(idx + 2) * BATCH + r0 + b) * 6 + m]);
            }
            if (idx < 9) {                   // ground-truth tactile for step idx+1
                for (int i = tid; i < BTILE * 48; i += BT) {
                    int b = i / 48, j = i - b * 48;
                    unsigned short v = f2bf(tact[((size_t)(idx + 1) * BATCH + r0 + b) * 48 + j]);
                    xbuf[b * XS + j] = v;
                    h2cat[p ^ 1][b * H2S + 208 + j] = v;
                }
            }
        }
        __syncthreads();

        // ---- P4: FC2 (o3|1) -> out4 ; emit + feedback ----
        if (wid < 3) {
            const int n = wid * 16 + lrow;   // 0..47
            bf16x8 wf[7];
#pragma unroll
            for (int kc = 0; kc < 7; ++kc) wf[kc] = *(const bf16x8*)(tf2 + kc * 512);
            f32x4 a0c = {0.f,0.f,0.f,0.f}, a1c = {0.f,0.f,0.f,0.f};
#pragma unroll
            for (int kc = 0; kc < 7; ++kc) {
                const int koff = kc * 32 + lgrp * 8;
                bf16x8 a0 = *(const bf16x8*)(o3buf + lrow * OS + koff);
                bf16x8 a1 = *(const bf16x8*)(o3buf + (lrow + 16) * OS + koff);
                a0c = __builtin_amdgcn_mfma_f32_16x16x32_bf16(a0, wf[kc], a0c, 0, 0, 0);
                a1c = __builtin_amdgcn_mfma_f32_16x16x32_bf16(a1, wf[kc], a1c, 0, 0, 0);
            }
            if (idx >= 9) {
#pragma unroll
                for (int m = 0; m < 2; ++m)
#pragma unroll
                for (int r = 0; r < 4; ++r) {
                    const int row = m * 16 + lgrp * 4 + r;
                    float o4 = tanh_(m == 0 ? a0c[r] : a1c[r]);
                    out[((size_t)(idx - 9) * BATCH + r0 + row) * 48 + n] = o4;
                    unsigned short v = f2bf(o4);
                    xbuf[row * XS + n] = v;
                    h2cat[p ^ 1][row * H2S + 208 + n] = v;
                }
            }
        }
        __syncthreads();
    }
}

extern "C" void kernel_launch(void* const* d_in, const int* in_sizes, int n_in,
                              void* d_out, int out_size, void* d_ws, size_t ws_size,
                              hipStream_t stream) {
    (void)in_sizes; (void)n_in; (void)out_size; (void)ws_size;
    const float* tact = (const float*)d_in[0];
    const float* acts = (const float*)d_in[1];
    const float* wih1 = (const float*)d_in[2];
    const float* whh1 = (const float*)d_in[3];
    const float* bih1 = (const float*)d_in[4];
    const float* bhh1 = (const float*)d_in[5];
    const float* wih2 = (const float*)d_in[6];
    const float* whh2 = (const float*)d_in[7];
    const float* bih2 = (const float*)d_in[8];
    const float* bhh2 = (const float*)d_in[9];
    const float* fc1w = (const float*)d_in[10];
    const float* fc1b = (const float*)d_in[11];
    const float* fc2w = (const float*)d_in[12];
    const float* fc2b = (const float*)d_in[13];
    unsigned short* ws = (unsigned short*)d_ws;
    float* outp = (float*)d_out;

    actp_prep<<<(WTOT + 255) / 256, 256, 0, stream>>>(wih1, whh1, bih1, bhh1,
                                                      wih2, whh2, bih2, bhh2,
                                                      fc1w, fc1b, fc2w, fc2b, ws);
    actp_main<<<BATCH / BTILE, BT, 0, stream>>>(tact, acts, ws, outp);
}

// Round 5
// 918.469 us; speedup vs baseline: 1.9690x; 1.9386x over previous
//
#include <hip/hip_runtime.h>

#define BATCH 8192
#define NSTEP 29
#define BTILE 32
#define BT    1024         // 16 waves
#define XS    72           // x stride (bf16): [0,48)=tactile/out4, [48,54)=act, [54,60)=state, [60]=1
#define HS    232          // h1 stride: [0,200)=h, [208]=1
#define H2S   296          // h2cat stride: [0,200)=h2, [208,256)=inp, [256]=1
#define OS    232          // o3 stride: [0,200)=o3, [208]=1

// fragment-packed weights: each (tile,kc,gate) = 512 contiguous elems (lane*8+e)
#define OW1   0            // W1: [13][9][4][512]
#define OW2   239616       // W2: [13][14][4][512]
#define OF1   612352       // FC1: [13][9][512]
#define OF2   672256       // FC2: [3][7][512]
#define WTOT  683008

typedef __bf16 bf16x8 __attribute__((ext_vector_type(8)));
typedef float  f32x4  __attribute__((ext_vector_type(4)));

__device__ __forceinline__ unsigned short f2bf(float f) {
    union { float f; unsigned u; } v; v.f = f;
    unsigned r = v.u + 0x7fffu + ((v.u >> 16) & 1u);
    return (unsigned short)(r >> 16);
}
__device__ __forceinline__ float sigf(float x) { return 1.0f / (1.0f + __expf(-x)); }
__device__ __forceinline__ float tanh_(float x) {
    x = fminf(15.0f, fmaxf(-15.0f, x));
    float e = __expf(2.0f * x);
    return (e - 1.0f) / (e + 1.0f);
}

// 4 coalesced 16B weight loads, issue order pinned by asm volatile
__device__ __forceinline__ void load4(bf16x8 &w0, bf16x8 &w1, bf16x8 &w2, bf16x8 &w3,
                                      const unsigned short* p) {
    asm volatile("global_load_dwordx4 %0, %4, off\n\t"
                 "global_load_dwordx4 %1, %4, off offset:1024\n\t"
                 "global_load_dwordx4 %2, %4, off offset:2048\n\t"
                 "global_load_dwordx4 %3, %4, off offset:3072"
                 : "=&v"(w0), "=&v"(w1), "=&v"(w2), "=&v"(w3)
                 : "v"(p));
}
__device__ __forceinline__ void load1(bf16x8 &w, const unsigned short* p) {
    asm volatile("global_load_dwordx4 %0, %1, off" : "=&v"(w) : "v"(p));
}

// repack weights into per-wave fragment order (coalesced 1KB bursts), bias folded as K-col
__global__ void actp_prep(const float* __restrict__ wih1, const float* __restrict__ whh1,
                          const float* __restrict__ bih1, const float* __restrict__ bhh1,
                          const float* __restrict__ wih2, const float* __restrict__ whh2,
                          const float* __restrict__ bih2, const float* __restrict__ bhh2,
                          const float* __restrict__ fc1w, const float* __restrict__ fc1b,
                          const float* __restrict__ fc2w, const float* __restrict__ fc2b,
                          unsigned short* __restrict__ ws) {
    int i = blockIdx.x * 256 + threadIdx.x;
    if (i >= WTOT) return;
    float v = 0.f;
    if (i < OW2) {                               // W1 [13][9][4][512], K: x(64)|h1(224)
        int blk = i >> 9, le = i & 511;
        int lane = le >> 3, e = le & 7;
        int g = blk & 3, t2 = blk >> 2;
        int kc = t2 % 9, jt = t2 / 9;
        int n = jt * 16 + (lane & 15), k = kc * 32 + (lane >> 4) * 8 + e;
        if (n < 200) {
            int o = g * 200 + n;
            if (k < 60)                   v = wih1[o * 60 + k];
            else if (k == 60)             v = bih1[o] + bhh1[o];
            else if (k >= 64 && k < 264)  v = whh1[o * 200 + (k - 64)];
        }
    } else if (i < OF1) {                        // W2 [13][14][4][512], K: h1(224)|h2(224)
        int j = i - OW2;
        int blk = j >> 9, le = j & 511;
        int lane = le >> 3, e = le & 7;
        int g = blk & 3, t2 = blk >> 2;
        int kc = t2 % 14, jt = t2 / 14;
        int n = jt * 16 + (lane & 15), k = kc * 32 + (lane >> 4) * 8 + e;
        if (n < 200) {
            int o = g * 200 + n;
            if (k < 200)                   v = wih2[o * 200 + k];
            else if (k == 208)             v = bih2[o] + bhh2[o];
            else if (k >= 224 && k < 424)  v = whh2[o * 200 + (k - 224)];
        }
    } else if (i < OF2) {                        // FC1 [13][9][512]
        int j = i - OF1;
        int blk = j >> 9, le = j & 511;
        int lane = le >> 3, e = le & 7;
        int kc = blk % 9, jt = blk / 9;
        int n = jt * 16 + (lane & 15), k = kc * 32 + (lane >> 4) * 8 + e;
        if (n < 200) {
            if (k < 200)                   v = fc1w[n * 248 + k];
            else if (k >= 208 && k < 256)  v = fc1w[n * 248 + 200 + (k - 208)];
            else if (k == 256)             v = fc1b[n];
        }
    } else {                                     // FC2 [3][7][512]
        int j = i - OF2;
        int blk = j >> 9, le = j & 511;
        int lane = le >> 3, e = le & 7;
        int kc = blk % 7, nt = blk / 7;
        int n = nt * 16 + (lane & 15), k = kc * 32 + (lane >> 4) * 8 + e;
        if (k < 200)       v = fc2w[n * 200 + k];
        else if (k == 208) v = fc2b[n];
    }
    ws[i] = (v == 0.f) ? (unsigned short)0 : f2bf(v);
}

// 4-gate MFMA tile, hand-pipelined weight stream (PF=2 kc-groups ahead,
// counted vmcnt never 0 mid-loop), in-register LSTM elementwise.
template<int NKC, int SPLIT, int SA0, int SA1, int KOFF1>
__device__ __forceinline__ void lstm_tile(
    const unsigned short* a0buf, const unsigned short* a1buf,
    const unsigned short* bp,
    const int lrow, const int lgrp,
    float (&cst)[2][4],
    unsigned short* hout, const int hstride, const int jcol)
{
    f32x4 acc[4][2];
#pragma unroll
    for (int g = 0; g < 4; ++g) { acc[g][0] = {0.f,0.f,0.f,0.f}; acc[g][1] = {0.f,0.f,0.f,0.f}; }

    bf16x8 wb[3][4];
    load4(wb[0][0], wb[0][1], wb[0][2], wb[0][3], bp);
    load4(wb[1][0], wb[1][1], wb[1][2], wb[1][3], bp + 2048);

#pragma unroll
    for (int kc = 0; kc < NKC; ++kc) {
        if (kc + 2 < NKC) {
            const int s = (kc + 2) % 3;
            load4(wb[s][0], wb[s][1], wb[s][2], wb[s][3], bp + (kc + 2) * 2048);
        }
        const int koff = kc * 32 + lgrp * 8;
        bf16x8 a0, a1;
        if (kc < SPLIT) {
            a0 = *(const bf16x8*)(a0buf + lrow * SA0 + koff);
            a1 = *(const bf16x8*)(a0buf + (lrow + 16) * SA0 + koff);
        } else {
            a0 = *(const bf16x8*)(a1buf + lrow * SA1 + koff - KOFF1);
            a1 = *(const bf16x8*)(a1buf + (lrow + 16) * SA1 + koff - KOFF1);
        }
        // group kc complete when outstanding <= 4 * (groups issued after kc)
        asm volatile("s_waitcnt vmcnt(%0)"
                     :: "i"(4 * (((kc + 3 < NKC) ? (kc + 3) : NKC) - kc - 1)));
        __builtin_amdgcn_sched_barrier(0);
        const int slot = kc % 3;
#pragma unroll
        for (int g = 0; g < 4; ++g) {
            acc[g][0] = __builtin_amdgcn_mfma_f32_16x16x32_bf16(a0, wb[slot][g], acc[g][0], 0, 0, 0);
            acc[g][1] = __builtin_amdgcn_mfma_f32_16x16x32_bf16(a1, wb[slot][g], acc[g][1], 0, 0, 0);
        }
    }
#pragma unroll
    for (int m = 0; m < 2; ++m)
#pragma unroll
    for (int r = 0; r < 4; ++r) {
        float c = sigf(acc[1][m][r]) * cst[m][r] + sigf(acc[0][m][r]) * tanh_(acc[2][m][r]);
        cst[m][r] = c;
        hout[(m * 16 + lgrp * 4 + r) * hstride + jcol] = f2bf(sigf(acc[3][m][r]) * tanh_(c));
    }
}

__global__ __launch_bounds__(BT, 4) void actp_main(
    const float* __restrict__ tact, const float* __restrict__ acts,
    const unsigned short* __restrict__ ws, float* __restrict__ out)
{
    __shared__ alignas(16) unsigned short xbuf[BTILE * XS];
    __shared__ alignas(16) unsigned short h1buf[2][BTILE * HS];
    __shared__ alignas(16) unsigned short h2cat[2][BTILE * H2S];
    __shared__ alignas(16) unsigned short o3buf[BTILE * OS];

    const int tid  = threadIdx.x;
    const int lane = tid & 63;
    const int wid  = tid >> 6;      // 0..15
    const int lrow = lane & 15;
    const int lgrp = lane >> 4;
    const int r0   = blockIdx.x * BTILE;

    // per-wave fragment-packed weight bases (include lane*8)
    const unsigned short* tb1 = ws + OW1 + wid * (9 * 4 * 512)  + (lane << 3);
    const unsigned short* tb2 = ws + OW2 + wid * (14 * 4 * 512) + (lane << 3);
    const unsigned short* tf1 = ws + OF1 + wid * (9 * 512)      + (lane << 3);
    const unsigned short* tf2 = ws + OF2 + (wid < 3 ? wid : 0) * (7 * 512) + (lane << 3);

    // ---- prologue ----
    for (int i = tid; i < BTILE * XS;      i += BT) xbuf[i] = 0;
    for (int i = tid; i < 2 * BTILE * HS;  i += BT) h1buf[0][i] = 0;
    for (int i = tid; i < 2 * BTILE * H2S; i += BT) h2cat[0][i] = 0;
    for (int i = tid; i < BTILE * OS;      i += BT) o3buf[i] = 0;
    __syncthreads();
    if (tid < BTILE) {
        const unsigned short ONE = 0x3F80;
        xbuf[tid * XS + 60] = ONE;
        h1buf[0][tid * HS + 208] = ONE;  h1buf[1][tid * HS + 208] = ONE;
        h2cat[0][tid * H2S + 256] = ONE; h2cat[1][tid * H2S + 256] = ONE;
        o3buf[tid * OS + 208] = ONE;
    }
    if (tid < BTILE * 6) {
        int b = tid / 6, m = tid - b * 6;
        xbuf[b * XS + 54 + m] = f2bf(acts[(size_t)(r0 + b) * 6 + m]);                 // state = acts[0]
        xbuf[b * XS + 48 + m] = f2bf(acts[((size_t)1 * BATCH + r0 + b) * 6 + m]);     // action step 0
    }
    for (int i = tid; i < BTILE * 48; i += BT) {
        int b = i / 48, j = i - b * 48;
        unsigned short v = f2bf(tact[(size_t)(r0 + b) * 48 + j]);                      // tact[0]
        xbuf[b * XS + j] = v;
        h2cat[0][b * H2S + 208 + j] = v;
    }
    __syncthreads();

    float c1[2][4], c2[2][4];
#pragma unroll
    for (int m = 0; m < 2; ++m)
#pragma unroll
    for (int r = 0; r < 4; ++r) { c1[m][r] = 0.f; c2[m][r] = 0.f; }

    for (int idx = 0; idx < NSTEP; ++idx) {
        const int p = idx & 1;
        unsigned short* h1n = h1buf[p];
        unsigned short* h1o = h1buf[p ^ 1];
        unsigned short* h2n = h2cat[p];
        unsigned short* h2o = h2cat[p ^ 1];

        // ---- P1: LSTM1 (x | h1_old) -> h1_new ----
        if (wid < 13) {
            const int n = wid * 16 + lrow;
            lstm_tile<9, 2, XS, HS, 64>(xbuf, h1o, tb1, lrow, lgrp, c1, h1n, HS, n);
        }
        __syncthreads();

        // ---- P2: LSTM2 (h1_new | h2_old) -> h2_new ----
        if (wid < 13) {
            const int n = wid * 16 + lrow;
            lstm_tile<14, 7, HS, H2S, 224>(h1n, h2o, tb2, lrow, lgrp, c2, h2n, H2S, n);
        }
        __syncthreads();

        // ---- P3: FC1 (h2_new|inp|1) -> o3 ; next-step input preloads ----
        if (wid < 13) {
            const int n = wid * 16 + lrow;
            bf16x8 wf[9];
#pragma unroll
            for (int kc = 0; kc < 9; ++kc) load1(wf[kc], tf1 + kc * 512);
            f32x4 a0c = {0.f,0.f,0.f,0.f}, a1c = {0.f,0.f,0.f,0.f};
#pragma unroll
            for (int kc = 0; kc < 9; ++kc) {
                const int koff = kc * 32 + lgrp * 8;
                bf16x8 a0 = *(const bf16x8*)(h2n + lrow * H2S + koff);
                bf16x8 a1 = *(const bf16x8*)(h2n + (lrow + 16) * H2S + koff);
                asm volatile("s_waitcnt vmcnt(%0)" :: "i"(8 - kc));
                __builtin_amdgcn_sched_barrier(0);
                a0c = __builtin_amdgcn_mfma_f32_16x16x32_bf16(a0, wf[kc], a0c, 0, 0, 0);
                a1c = __builtin_amdgcn_mfma_f32_16x16x32_bf16(a1, wf[kc], a1c, 0, 0, 0);
            }
#pragma unroll
            for (int r = 0; r < 4; ++r) {
                o3buf[(lgrp * 4 + r) * OS + n]      = f2bf(tanh_(a0c[r]));
                o3buf[(16 + lgrp * 4 + r) * OS + n] = f2bf(tanh_(a1c[r]));
            }
        }
        if (idx < NSTEP - 1) {
            if (tid < BTILE * 6) {           // action for step idx+1 = acts[idx+2]
                int b = tid / 6, m = tid - b * 6;
                xbuf[b * XS + 48 + m] = f2bf(acts[((size_t)(idx + 2) * BATCH + r0 + b) * 6 + m]);
            }
            if (idx < 9) {                   // ground-truth tactile for step idx+1
                for (int i = tid; i < BTILE * 48; i += BT) {
                    int b = i / 48, j = i - b * 48;
                    unsigned short v = f2bf(tact[((size_t)(idx + 1) * BATCH + r0 + b) * 48 + j]);
                    xbuf[b * XS + j] = v;
                    h2cat[p ^ 1][b * H2S + 208 + j] = v;
                }
            }
        }
        __syncthreads();

        // ---- P4: FC2 (o3|1) -> out4 ; emit + feedback ----
        if (wid < 3) {
            const int n = wid * 16 + lrow;   // 0..47
            bf16x8 wf[7];
#pragma unroll
            for (int kc = 0; kc < 7; ++kc) load1(wf[kc], tf2 + kc * 512);
            f32x4 a0c = {0.f,0.f,0.f,0.f}, a1c = {0.f,0.f,0.f,0.f};
#pragma unroll
            for (int kc = 0; kc < 7; ++kc) {
                const int koff = kc * 32 + lgrp * 8;
                bf16x8 a0 = *(const bf16x8*)(o3buf + lrow * OS + koff);
                bf16x8 a1 = *(const bf16x8*)(o3buf + (lrow + 16) * OS + koff);
                asm volatile("s_waitcnt vmcnt(%0)" :: "i"(6 - kc));
                __builtin_amdgcn_sched_barrier(0);
                a0c = __builtin_amdgcn_mfma_f32_16x16x32_bf16(a0, wf[kc], a0c, 0, 0, 0);
                a1c = __builtin_amdgcn_mfma_f32_16x16x32_bf16(a1, wf[kc], a1c, 0, 0, 0);
            }
            if (idx >= 9) {
#pragma unroll
                for (int m = 0; m < 2; ++m)
#pragma unroll
                for (int r = 0; r < 4; ++r) {
                    const int row = m * 16 + lgrp * 4 + r;
                    float o4 = tanh_(m == 0 ? a0c[r] : a1c[r]);
                    out[((size_t)(idx - 9) * BATCH + r0 + row) * 48 + n] = o4;
                    unsigned short v = f2bf(o4);
                    xbuf[row * XS + n] = v;
                    h2cat[p ^ 1][row * H2S + 208 + n] = v;
                }
            }
        }
        __syncthreads();
    }
}

extern "C" void kernel_launch(void* const* d_in, const int* in_sizes, int n_in,
                              void* d_out, int out_size, void* d_ws, size_t ws_size,
                              hipStream_t stream) {
    (void)in_sizes; (void)n_in; (void)out_size; (void)ws_size;
    const float* tact = (const float*)d_in[0];
    const float* acts = (const float*)d_in[1];
    const float* wih1 = (const float*)d_in[2];
    const float* whh1 = (const float*)d_in[3];
    const float* bih1 = (const float*)d_in[4];
    const float* bhh1 = (const float*)d_in[5];
    const float* wih2 = (const float*)d_in[6];
    const float* whh2 = (const float*)d_in[7];
    const float* bih2 = (const float*)d_in[8];
    const float* bhh2 = (const float*)d_in[9];
    const float* fc1w = (const float*)d_in[10];
    const float* fc1b = (const float*)d_in[11];
    const float* fc2w = (const float*)d_in[12];
    const float* fc2b = (const float*)d_in[13];
    unsigned short* ws = (unsigned short*)d_ws;
    float* outp = (float*)d_out;

    actp_prep<<<(WTOT + 255) / 256, 256, 0, stream>>>(wih1, whh1, bih1, bhh1,
                                                      wih2, whh2, bih2, bhh2,
                                                      fc1w, fc1b, fc2w, fc2b, ws);
    actp_main<<<BATCH / BTILE, BT, 0, stream>>>(tact, acts, ws, outp);
}